// Round 1
// baseline (537.129 us; speedup 1.0000x reference)
//
#include <hip/hip_runtime.h>
#include <cstdint>
#include <cstddef>

typedef unsigned short u16;
typedef unsigned int u32;
typedef __bf16 bf16x8 __attribute__((ext_vector_type(8)));
typedef float floatx4 __attribute__((ext_vector_type(4)));

#define B_ 2
#define S_ 2048
#define D_ 1024
#define H_ 16
#define DFF_ 4096
#define BS_ 4096   // B_*S_

__device__ __forceinline__ u16 f2bf(float f) {
  u32 u = __builtin_bit_cast(u32, f);
  u += 0x7fffu + ((u >> 16) & 1u);
  return (u16)(u >> 16);
}
__device__ __forceinline__ float bf2f(u16 h) {
  u32 u = ((u32)h) << 16;
  return __builtin_bit_cast(float, u);
}

// ---------------------------------------------------------------------------
// Transpose + fp32->bf16 cast: in [R][C] f32 row-major -> out [C][R] bf16.
// ---------------------------------------------------------------------------
__global__ void transpose_cast(const float* __restrict__ in, u16* __restrict__ out,
                               int R, int C) {
  __shared__ float tile[32][33];
  const int tx = threadIdx.x, ty = threadIdx.y;
  const int c0 = blockIdx.x * 32, r0 = blockIdx.y * 32;
#pragma unroll
  for (int i = 0; i < 4; i++)
    tile[ty + i * 8][tx] = in[(size_t)(r0 + ty + i * 8) * C + c0 + tx];
  __syncthreads();
#pragma unroll
  for (int i = 0; i < 4; i++)
    out[(size_t)(c0 + ty + i * 8) * R + r0 + tx] = f2bf(tile[tx][ty + i * 8]);
}

// ---------------------------------------------------------------------------
// RMSNorm: x [rows][1024] f32, g [1024] f32 -> out bf16 [rows][1024]
// ---------------------------------------------------------------------------
__global__ __launch_bounds__(256) void rmsnorm_kernel(const float* __restrict__ x,
                                                      const float* __restrict__ g,
                                                      u16* __restrict__ out) {
  const int row = blockIdx.x, t = threadIdx.x;
  const float4 v = ((const float4*)(x + (size_t)row * 1024))[t];
  float ss = v.x * v.x + v.y * v.y + v.z * v.z + v.w * v.w;
#pragma unroll
  for (int off = 32; off > 0; off >>= 1) ss += __shfl_xor(ss, off);
  __shared__ float red[4];
  if ((t & 63) == 0) red[t >> 6] = ss;
  __syncthreads();
  ss = red[0] + red[1] + red[2] + red[3];
  const float inv = rsqrtf(ss * (1.0f / 1024.0f) + 1e-6f);
  const float4 gv = ((const float4*)g)[t];
  uint2 o;
  o.x = (u32)f2bf(v.x * inv * gv.x) | ((u32)f2bf(v.y * inv * gv.y) << 16);
  o.y = (u32)f2bf(v.z * inv * gv.z) | ((u32)f2bf(v.w * inv * gv.w) << 16);
  ((uint2*)(out + (size_t)row * 1024))[t] = o;
}

// ---------------------------------------------------------------------------
// bf16 GEMM: C[M,N] = A[M,K] @ Bt[N,K]^T.  128x128 tile, 4 waves, 16x16x32 MFMA.
// EPI 0: store bf16.  EPI 1: store f32 with f32 residual add.
// LDS XOR-swizzle (chunk c at slot c ^ ((row>>1)&3)) kills ds_read_b128
// bank conflicts at stride-64B rows while keeping 16B alignment.
// ---------------------------------------------------------------------------
template <int EPI>
__global__ __launch_bounds__(256) void gemm_bt(const u16* __restrict__ A,
                                               const u16* __restrict__ Bt,
                                               void* __restrict__ Cout,
                                               const float* __restrict__ res,
                                               int M, int N, int K) {
  __shared__ u16 As[128 * 32];
  __shared__ u16 Bs[128 * 32];
  const int t = threadIdx.x;
  const int w = t >> 6, l = t & 63;
  const int wm = w >> 1, wn = w & 1;
  const int m0 = blockIdx.y * 128, n0 = blockIdx.x * 128;
  const int lrow = l & 15, lk = l >> 4;

  floatx4 acc[4][4] = {};

  // staging: 512 chunks of 16B per tile; thread handles chunks t and t+256
  const int ar0 = t >> 2, ac0 = t & 3;
  const int ar1 = ar0 + 64, ac1 = ac0;
  const int sa0 = ar0 * 32 + ((ac0 ^ ((ar0 >> 1) & 3)) << 3);
  const int sa1 = ar1 * 32 + ((ac1 ^ ((ar1 >> 1) & 3)) << 3);

  for (int kk = 0; kk < K; kk += 32) {
    const uint4 a0 = *(const uint4*)(A + (size_t)(m0 + ar0) * K + kk + ac0 * 8);
    const uint4 a1 = *(const uint4*)(A + (size_t)(m0 + ar1) * K + kk + ac1 * 8);
    const uint4 b0 = *(const uint4*)(Bt + (size_t)(n0 + ar0) * K + kk + ac0 * 8);
    const uint4 b1 = *(const uint4*)(Bt + (size_t)(n0 + ar1) * K + kk + ac1 * 8);
    __syncthreads();
    *(uint4*)(As + sa0) = a0;
    *(uint4*)(As + sa1) = a1;
    *(uint4*)(Bs + sa0) = b0;
    *(uint4*)(Bs + sa1) = b1;
    __syncthreads();

    bf16x8 af[4], bfr[4];
#pragma unroll
    for (int mi = 0; mi < 4; mi++) {
      const int r = wm * 64 + mi * 16 + lrow;
      af[mi] = *(const bf16x8*)(As + r * 32 + ((lk ^ ((r >> 1) & 3)) << 3));
    }
#pragma unroll
    for (int ni = 0; ni < 4; ni++) {
      const int r = wn * 64 + ni * 16 + lrow;
      bfr[ni] = *(const bf16x8*)(Bs + r * 32 + ((lk ^ ((r >> 1) & 3)) << 3));
    }
#pragma unroll
    for (int mi = 0; mi < 4; mi++)
#pragma unroll
      for (int ni = 0; ni < 4; ni++)
        acc[mi][ni] = __builtin_amdgcn_mfma_f32_16x16x32_bf16(af[mi], bfr[ni],
                                                              acc[mi][ni], 0, 0, 0);
  }

#pragma unroll
  for (int mi = 0; mi < 4; mi++)
#pragma unroll
    for (int ni = 0; ni < 4; ni++)
#pragma unroll
      for (int r = 0; r < 4; r++) {
        const int row = m0 + wm * 64 + mi * 16 + lk * 4 + r;
        const int col = n0 + wn * 64 + ni * 16 + lrow;
        const size_t idx = (size_t)row * N + col;
        float v = acc[mi][ni][r];
        if (EPI == 0) {
          ((u16*)Cout)[idx] = f2bf(v);
        } else {
          ((float*)Cout)[idx] = v + res[idx];
        }
      }
}

// ---------------------------------------------------------------------------
// Causal attention (strict: k < q), softmax = exp(s)/(sum+1e-9), no max-sub.
// qkv bf16 [BS_][3072] (q|k|v each H*64). av bf16 [BS_][1024].
// Block: (qt, h, b), 64 queries, 4 waves (16 q-rows each). K/V tiles of 64.
// ---------------------------------------------------------------------------
__global__ __launch_bounds__(256) void attn_kernel(const u16* __restrict__ qkv,
                                                   u16* __restrict__ av) {
  __shared__ u16 Ks[64 * 72];       // [kpos][dk], rows padded to 72
  __shared__ u16 Vt[64 * 72];       // [dv][kpos], rows padded to 72
  __shared__ u16 Ps[4 * 16 * 72];   // per-wave P tile [16 q][64 k], padded
  const int t = threadIdx.x;
  const int w = t >> 6, l = t & 63;
  const int lrow = l & 15, lk = l >> 4;
  const int qt = blockIdx.x, h = blockIdx.y, b = blockIdx.z;

  // Q fragments (A-operand): row = lrow, dk halves
  const int qrow_g = b * S_ + qt * 64 + w * 16 + lrow;
  const u16* qptr = qkv + (size_t)qrow_g * 3072 + h * 64;
  const bf16x8 aq0 = *(const bf16x8*)(qptr + lk * 8);
  const bf16x8 aq1 = *(const bf16x8*)(qptr + 32 + lk * 8);

  floatx4 oacc[4] = {};
  float den[4] = {0.f, 0.f, 0.f, 0.f};

  const int r0 = t >> 3, c0 = t & 7;  // staging: row r0/r0+32, 16B chunk c0
  const int r1 = r0 + 32;

  for (int kt = 0; kt <= qt; kt++) {
    const size_t kb = (size_t)(b * S_ + kt * 64);
    const u16* kbase = qkv + kb * 3072 + D_ + h * 64;
    const u16* vbase = qkv + kb * 3072 + 2 * D_ + h * 64;
    const uint4 kv0 = *(const uint4*)(kbase + (size_t)r0 * 3072 + c0 * 8);
    const uint4 kv1 = *(const uint4*)(kbase + (size_t)r1 * 3072 + c0 * 8);
    const uint4 vv0 = *(const uint4*)(vbase + (size_t)r0 * 3072 + c0 * 8);
    const uint4 vv1 = *(const uint4*)(vbase + (size_t)r1 * 3072 + c0 * 8);
    __syncthreads();
    *(uint4*)(Ks + r0 * 72 + c0 * 8) = kv0;
    *(uint4*)(Ks + r1 * 72 + c0 * 8) = kv1;
    {
      union { uint4 u; u16 s[8]; } x;
      x.u = vv0;
#pragma unroll
      for (int j = 0; j < 8; j++) Vt[(c0 * 8 + j) * 72 + r0] = x.s[j];
      x.u = vv1;
#pragma unroll
      for (int j = 0; j < 8; j++) Vt[(c0 * 8 + j) * 72 + r1] = x.s[j];
    }
    __syncthreads();

    // S = Q K^T, mask, exp -> P (bf16 in LDS), den accumulation
#pragma unroll
    for (int ct = 0; ct < 4; ct++) {
      const u16* kr = Ks + (ct * 16 + lrow) * 72 + lk * 8;
      const bf16x8 bk0 = *(const bf16x8*)(kr);
      const bf16x8 bk1 = *(const bf16x8*)(kr + 32);
      floatx4 s = {};
      s = __builtin_amdgcn_mfma_f32_16x16x32_bf16(aq0, bk0, s, 0, 0, 0);
      s = __builtin_amdgcn_mfma_f32_16x16x32_bf16(aq1, bk1, s, 0, 0, 0);
      const int kpos = kt * 64 + ct * 16 + lrow;
#pragma unroll
      for (int r = 0; r < 4; r++) {
        const int qpos = qt * 64 + w * 16 + lk * 4 + r;
        const float p = (kpos < qpos) ? __expf(s[r] * 0.125f) : 0.f;
        den[r] += p;
        Ps[w * 1152 + (lk * 4 + r) * 72 + ct * 16 + lrow] = f2bf(p);
      }
    }

    // P V: P as A-operand (round-trip through LDS), V^T as B-operand
    const bf16x8 ap0 = *(const bf16x8*)(Ps + w * 1152 + lrow * 72 + lk * 8);
    const bf16x8 ap1 = *(const bf16x8*)(Ps + w * 1152 + lrow * 72 + 32 + lk * 8);
#pragma unroll
    for (int ni = 0; ni < 4; ni++) {
      const u16* vr = Vt + (ni * 16 + lrow) * 72 + lk * 8;
      const bf16x8 bv0 = *(const bf16x8*)(vr);
      const bf16x8 bv1 = *(const bf16x8*)(vr + 32);
      oacc[ni] = __builtin_amdgcn_mfma_f32_16x16x32_bf16(ap0, bv0, oacc[ni], 0, 0, 0);
      oacc[ni] = __builtin_amdgcn_mfma_f32_16x16x32_bf16(ap1, bv1, oacc[ni], 0, 0, 0);
    }
  }

  // reduce den across the 16 lanes sharing a row-group (xor low 4 bits)
#pragma unroll
  for (int r = 0; r < 4; r++) {
    float d = den[r];
    d += __shfl_xor(d, 1);
    d += __shfl_xor(d, 2);
    d += __shfl_xor(d, 4);
    d += __shfl_xor(d, 8);
    den[r] = d;
  }
#pragma unroll
  for (int ni = 0; ni < 4; ni++)
#pragma unroll
    for (int r = 0; r < 4; r++) {
      const int row = qt * 64 + w * 16 + lk * 4 + r;
      const int col = h * 64 + ni * 16 + lrow;
      av[(size_t)(b * S_ + row) * 1024 + col] = f2bf(oacc[ni][r] / (den[r] + 1e-9f));
    }
}

// ---------------------------------------------------------------------------
// SiLU(gate) * up: ff bf16 [4096][8192] (gate|up) -> hidden bf16 [4096][4096]
// ---------------------------------------------------------------------------
__global__ __launch_bounds__(256) void silumul_kernel(const u16* __restrict__ ff,
                                                      u16* __restrict__ hidden) {
  const int idx = blockIdx.x * 256 + threadIdx.x;  // 8-element groups
  const int row = idx >> 9, cj = idx & 511;
  union { uint4 u; u16 s[8]; } gx, ux, o;
  gx.u = *(const uint4*)(ff + (size_t)row * 8192 + cj * 8);
  ux.u = *(const uint4*)(ff + (size_t)row * 8192 + 4096 + cj * 8);
#pragma unroll
  for (int j = 0; j < 8; j++) {
    const float gf = bf2f(gx.s[j]);
    const float uf = bf2f(ux.s[j]);
    const float sv = gf / (1.f + __expf(-gf));
    o.s[j] = f2bf(sv * uf);
  }
  *(uint4*)(hidden + (size_t)row * 4096 + cj * 8) = o.u;
}

// ---------------------------------------------------------------------------
// Workspace layout (bytes)
// ---------------------------------------------------------------------------
#define OFF_WQKV 0u                    // [3072][1024] bf16  (q^T|k^T|v^T)
#define OFF_WO   6291456u              // [1024][1024] bf16
#define OFF_WGU  8388608u              // [8192][1024] bf16  (gate^T|up^T)
#define OFF_WDN  25165824u             // [1024][4096] bf16
#define OFF_H1   33554432u             // [4096][1024] bf16
#define OFF_QKV  41943040u             // [4096][3072] bf16
#define OFF_AV   67108864u             // [4096][1024] bf16
#define OFF_X1   75497472u             // [4096][1024] f32
#define OFF_H2   92274688u             // [4096][1024] bf16
#define OFF_FF   100663296u            // [4096][8192] bf16
#define OFF_HID  167772160u            // [4096][4096] bf16

extern "C" void kernel_launch(void* const* d_in, const int* in_sizes, int n_in,
                              void* d_out, int out_size, void* d_ws, size_t ws_size,
                              hipStream_t stream) {
  const float* x      = (const float*)d_in[0];
  const float* w_q    = (const float*)d_in[1];
  const float* w_k    = (const float*)d_in[2];
  const float* w_v    = (const float*)d_in[3];
  const float* w_o    = (const float*)d_in[4];
  const float* w_gate = (const float*)d_in[5];
  const float* w_up   = (const float*)d_in[6];
  const float* w_down = (const float*)d_in[7];
  const float* g1     = (const float*)d_in[8];
  const float* g2     = (const float*)d_in[9];

  char* ws = (char*)d_ws;
  u16* wqkv_t = (u16*)(ws + OFF_WQKV);
  u16* wo_t   = (u16*)(ws + OFF_WO);
  u16* wgu_t  = (u16*)(ws + OFF_WGU);
  u16* wdn_t  = (u16*)(ws + OFF_WDN);
  u16* h1     = (u16*)(ws + OFF_H1);
  u16* qkv    = (u16*)(ws + OFF_QKV);
  u16* av     = (u16*)(ws + OFF_AV);
  float* x1   = (float*)(ws + OFF_X1);
  u16* h2     = (u16*)(ws + OFF_H2);
  u16* ffb    = (u16*)(ws + OFF_FF);
  u16* hid    = (u16*)(ws + OFF_HID);
  float* out  = (float*)d_out;

  const dim3 tb32(32, 8);
  // Weight transposes (+ bf16 cast)
  transpose_cast<<<dim3(32, 32), tb32, 0, stream>>>(w_q, wqkv_t, 1024, 1024);
  transpose_cast<<<dim3(32, 32), tb32, 0, stream>>>(w_k, wqkv_t + 1024 * 1024, 1024, 1024);
  transpose_cast<<<dim3(32, 32), tb32, 0, stream>>>(w_v, wqkv_t + 2 * 1024 * 1024, 1024, 1024);
  transpose_cast<<<dim3(32, 32), tb32, 0, stream>>>(w_o, wo_t, 1024, 1024);
  transpose_cast<<<dim3(128, 32), tb32, 0, stream>>>(w_gate, wgu_t, 1024, 4096);
  transpose_cast<<<dim3(128, 32), tb32, 0, stream>>>(w_up, wgu_t + 4096 * 1024, 1024, 4096);
  transpose_cast<<<dim3(32, 128), tb32, 0, stream>>>(w_down, wdn_t, 4096, 1024);

  // h1 = rmsnorm(x, g1)
  rmsnorm_kernel<<<BS_, 256, 0, stream>>>(x, g1, h1);
  // qkv = h1 @ [w_q|w_k|w_v]
  gemm_bt<0><<<dim3(3072 / 128, BS_ / 128), 256, 0, stream>>>(h1, wqkv_t, qkv, nullptr,
                                                              BS_, 3072, 1024);
  // attention
  attn_kernel<<<dim3(S_ / 64, H_, B_), 256, 0, stream>>>(qkv, av);
  // x1 = x + av @ w_o
  gemm_bt<1><<<dim3(1024 / 128, BS_ / 128), 256, 0, stream>>>(av, wo_t, x1, x,
                                                              BS_, 1024, 1024);
  // h2 = rmsnorm(x1, g2)
  rmsnorm_kernel<<<BS_, 256, 0, stream>>>(x1, g2, h2);
  // ff = h2 @ [w_gate|w_up]
  gemm_bt<0><<<dim3(8192 / 128, BS_ / 128), 256, 0, stream>>>(h2, wgu_t, ffb, nullptr,
                                                              BS_, 8192, 1024);
  // hidden = silu(gate) * up
  silumul_kernel<<<(BS_ * 512) / 256, 256, 0, stream>>>(ffb, hid);
  // out = x1 + hidden @ w_down
  gemm_bt<1><<<dim3(1024 / 128, BS_ / 128), 256, 0, stream>>>(hid, wdn_t, out, x1,
                                                              BS_, 1024, 4096);
}

// Round 2
// 455.267 us; speedup vs baseline: 1.1798x; 1.1798x over previous
//
#include <hip/hip_runtime.h>
#include <cstdint>
#include <cstddef>

typedef unsigned short u16;
typedef unsigned int u32;
typedef __bf16 bf16x8 __attribute__((ext_vector_type(8)));
typedef float floatx4 __attribute__((ext_vector_type(4)));

#define B_ 2
#define S_ 2048
#define D_ 1024
#define H_ 16
#define DFF_ 4096
#define BS_ 4096   // B_*S_

__device__ __forceinline__ u16 f2bf(float f) {
  u32 u = __builtin_bit_cast(u32, f);
  u += 0x7fffu + ((u >> 16) & 1u);
  return (u16)(u >> 16);
}
__device__ __forceinline__ float bf2f(u16 h) {
  u32 u = ((u32)h) << 16;
  return __builtin_bit_cast(float, u);
}

// async global->LDS, 16B per lane; LDS dest is wave-uniform base + lane*16
__device__ __forceinline__ void gl_lds16(const u16* g, u16* l) {
  __builtin_amdgcn_global_load_lds(
      (const __attribute__((address_space(1))) void*)g,
      (__attribute__((address_space(3))) void*)l, 16, 0, 0);
}

// ---------------------------------------------------------------------------
// Transpose + fp32->bf16 cast: in [R][C] f32 row-major -> out [C][R] bf16.
// mode 0: out row = c. mode 1 (gate): r' = (c>>4)*32 + (c&15).
// mode 2 (up):   r' = (c>>4)*32 + 16 + (c&15).   (16-col interleave for fusion)
// ---------------------------------------------------------------------------
__global__ void transpose_cast(const float* __restrict__ in, u16* __restrict__ out,
                               int R, int C, int mode) {
  __shared__ float tile[32][33];
  const int tx = threadIdx.x, ty = threadIdx.y;
  const int c0 = blockIdx.x * 32, r0 = blockIdx.y * 32;
#pragma unroll
  for (int i = 0; i < 4; i++)
    tile[ty + i * 8][tx] = in[(size_t)(r0 + ty + i * 8) * C + c0 + tx];
  __syncthreads();
#pragma unroll
  for (int i = 0; i < 4; i++) {
    const int oc = c0 + ty + i * 8;
    const int orow = (mode == 0) ? oc : ((oc >> 4) * 32 + (oc & 15) + (mode == 2 ? 16 : 0));
    out[(size_t)orow * R + r0 + tx] = f2bf(tile[tx][ty + i * 8]);
  }
}

// ---------------------------------------------------------------------------
// RMSNorm: x [rows][1024] f32, g [1024] f32 -> out bf16 [rows][1024]
// ---------------------------------------------------------------------------
__global__ __launch_bounds__(256) void rmsnorm_kernel(const float* __restrict__ x,
                                                      const float* __restrict__ g,
                                                      u16* __restrict__ out) {
  const int row = blockIdx.x, t = threadIdx.x;
  const float4 v = ((const float4*)(x + (size_t)row * 1024))[t];
  float ss = v.x * v.x + v.y * v.y + v.z * v.z + v.w * v.w;
#pragma unroll
  for (int off = 32; off > 0; off >>= 1) ss += __shfl_xor(ss, off);
  __shared__ float red[4];
  if ((t & 63) == 0) red[t >> 6] = ss;
  __syncthreads();
  ss = red[0] + red[1] + red[2] + red[3];
  const float inv = rsqrtf(ss * (1.0f / 1024.0f) + 1e-6f);
  const float4 gv = ((const float4*)g)[t];
  uint2 o;
  o.x = (u32)f2bf(v.x * inv * gv.x) | ((u32)f2bf(v.y * inv * gv.y) << 16);
  o.y = (u32)f2bf(v.z * inv * gv.z) | ((u32)f2bf(v.w * inv * gv.w) << 16);
  ((uint2*)(out + (size_t)row * 1024))[t] = o;
}

// ---------------------------------------------------------------------------
// V^T: qkv v-block [b,s,h,dv] -> vT [b][h][dv=64][S].  64x64 LDS tile.
// ---------------------------------------------------------------------------
__global__ __launch_bounds__(256) void vtrans_kernel(const u16* __restrict__ qkv,
                                                     u16* __restrict__ vT) {
  __shared__ u16 tile[64][72];
  const int t = threadIdx.x;
  const int s0 = blockIdx.x * 64, h = blockIdx.y, b = blockIdx.z;
  const int r = t >> 2, cc = t & 3;
  const u16* src = qkv + (size_t)(b * S_ + s0 + r) * 3072 + 2 * D_ + h * 64 + cc * 16;
  *(uint4*)(&tile[r][cc * 16]) = *(const uint4*)src;
  *(uint4*)(&tile[r][cc * 16 + 8]) = *(const uint4*)(src + 8);
  __syncthreads();
  union { uint4 u[2]; u16 s[16]; } o;
#pragma unroll
  for (int j = 0; j < 16; j++) o.s[j] = tile[cc * 16 + j][r];
  u16* dst = vT + (size_t)((b * H_ + h) * 64 + r) * S_ + s0 + cc * 16;
  *(uint4*)dst = o.u[0];
  *(uint4*)(dst + 8) = o.u[1];
}

// ---------------------------------------------------------------------------
// bf16 GEMM: C[M,N] = A[M,K] @ Bt[N,K]^T, m97-style global_load_lds staging.
// 128xBN tile, BK=32, 4 waves. EPI 0: bf16 out. EPI 1: f32 out + f32 residual.
// EPI 2: fused silu(gate)*up -> bf16 hid [M][4096] (gate/up 16-col interleave).
// ---------------------------------------------------------------------------
template <int BN, int EPI>
__global__ __launch_bounds__(256) void gemm_bt(const u16* __restrict__ A,
                                               const u16* __restrict__ Bt,
                                               void* __restrict__ Cout,
                                               const float* __restrict__ res,
                                               int M, int N, int K) {
  __shared__ u16 As[128 * 32];
  __shared__ u16 Bs[BN * 32];
  constexpr int NCH = 8 + BN / 16;   // 16B-chunk groups of 1024B (16 rows x 64B)
  constexpr int CPW = NCH / 4;
  constexpr int NI = BN / 32;
  const int t = threadIdx.x, w = t >> 6, l = t & 63;
  const int m0 = blockIdx.y * 128, n0 = blockIdx.x * BN;
  const int lrow = l & 15, lk = l >> 4;
  const int wm = w >> 1, wn = w & 1;

  const u16* gsrc[CPW];
  u16* ldst[CPW];
#pragma unroll
  for (int i = 0; i < CPW; i++) {
    const int c = w * CPW + i;
    if (c < 8) {
      gsrc[i] = A + (size_t)(m0 + c * 16 + (l >> 2)) * K + (l & 3) * 8;
      ldst[i] = As + c * 512;
    } else {
      const int cb = c - 8;
      gsrc[i] = Bt + (size_t)(n0 + cb * 16 + (l >> 2)) * K + (l & 3) * 8;
      ldst[i] = Bs + cb * 512;
    }
  }

  floatx4 acc[4][NI] = {};

  for (int kk = 0; kk < K; kk += 32) {
    __syncthreads();
#pragma unroll
    for (int i = 0; i < CPW; i++) gl_lds16(gsrc[i] + kk, ldst[i]);
    __syncthreads();

    bf16x8 af[4], bfr[NI];
#pragma unroll
    for (int mi = 0; mi < 4; mi++)
      af[mi] = *(const bf16x8*)(As + (wm * 64 + mi * 16 + lrow) * 32 + lk * 8);
#pragma unroll
    for (int ni = 0; ni < NI; ni++)
      bfr[ni] = *(const bf16x8*)(Bs + (wn * (BN / 2) + ni * 16 + lrow) * 32 + lk * 8);
#pragma unroll
    for (int mi = 0; mi < 4; mi++)
#pragma unroll
      for (int ni = 0; ni < NI; ni++)
        acc[mi][ni] = __builtin_amdgcn_mfma_f32_16x16x32_bf16(af[mi], bfr[ni],
                                                              acc[mi][ni], 0, 0, 0);
  }

  if (EPI == 2) {
    // gate = acc[mi][2j], up = acc[mi][2j+1]; col = (4*bx + 2*wn + j)*16 + lrow
#pragma unroll
    for (int mi = 0; mi < 4; mi++)
#pragma unroll
      for (int nj = 0; nj < NI / 2; nj++) {
        const int col = ((int)blockIdx.x * 4 + 2 * wn + nj) * 16 + lrow;
#pragma unroll
        for (int r = 0; r < 4; r++) {
          const int row = m0 + wm * 64 + mi * 16 + lk * 4 + r;
          const float g = acc[mi][2 * nj][r];
          const float u = acc[mi][2 * nj + 1][r];
          const float sv = g / (1.f + __expf(-g)) * u;
          ((u16*)Cout)[(size_t)row * 4096 + col] = f2bf(sv);
        }
      }
  } else {
#pragma unroll
    for (int mi = 0; mi < 4; mi++)
#pragma unroll
      for (int ni = 0; ni < NI; ni++)
#pragma unroll
        for (int r = 0; r < 4; r++) {
          const int row = m0 + wm * 64 + mi * 16 + lk * 4 + r;
          const int col = n0 + wn * (BN / 2) + ni * 16 + lrow;
          const size_t idx = (size_t)row * N + col;
          const float v = acc[mi][ni][r];
          if (EPI == 0) ((u16*)Cout)[idx] = f2bf(v);
          else          ((float*)Cout)[idx] = v + res[idx];
        }
  }
}

// ---------------------------------------------------------------------------
// Causal attention (strict k<q), softmax = exp(s)/(sum+1e-9), flash-style.
// q-tile 128 (wave owns 32 q rows), k-tile 64, double-buffered LDS staging of
// K [half][64][32] and V^T [khalf][64][32] via global_load_lds; one barrier
// per iter; P per-wave in XOR-swizzled LDS.
// ---------------------------------------------------------------------------
__global__ __launch_bounds__(256) void attn_kernel(const u16* __restrict__ qkv,
                                                   const u16* __restrict__ vT,
                                                   u16* __restrict__ av) {
  __shared__ u16 SM[2 * 8192];       // [buf][ K:2x64x32 | V:2x64x32 ]
  __shared__ u16 Ps[4 * 2048];       // per-wave P [32 q][64 k], 16B-chunk swizzle
  const int t = threadIdx.x, w = t >> 6, l = t & 63;
  const int lrow = l & 15, lk = l >> 4;
  const int bh = blockIdx.x;         // b*16 + h
  const int b = bh >> 4, h = bh & 15;
  const int qt = 15 - (int)blockIdx.y;   // heavy tiles dispatch first
  const int qbase = qt * 128 + w * 32;
  const int ktmax = 2 * qt + 1;
  u16* Pw = Ps + w * 2048;

  // Q fragments (A-operand), rows qbase + sub*16 + lrow
  bf16x8 aq[2][2];
#pragma unroll
  for (int sub = 0; sub < 2; sub++)
#pragma unroll
    for (int half = 0; half < 2; half++)
      aq[sub][half] = *(const bf16x8*)(qkv + (size_t)(b * S_ + qbase + sub * 16 + lrow) * 3072 +
                                       h * 64 + half * 32 + lk * 8);

  // staging chunks: c = w + 4*i; c<8 -> K(half=(c>>2)&1, grp=c&3), else V
  const u16* gcur[4];
  int gstep[4], loff[4];
#pragma unroll
  for (int i = 0; i < 4; i++) {
    const int c = w + 4 * i;
    const int half = (c >> 2) & 1, grp = c & 3;
    if (c < 8) {
      gcur[i] = qkv + (size_t)(b * S_ + grp * 16 + (l >> 2)) * 3072 + D_ + h * 64 +
                half * 32 + (l & 3) * 8;
      gstep[i] = 64 * 3072;
      loff[i] = half * 2048 + grp * 512;
    } else {
      gcur[i] = vT + (size_t)(bh * 64 + grp * 16 + (l >> 2)) * S_ + half * 32 + (l & 3) * 8;
      gstep[i] = 64;
      loff[i] = 4096 + half * 2048 + grp * 512;
    }
  }

  floatx4 oacc[2][4] = {};
  float den[2][4] = {};

  int cur = 0;
  // prologue: issue kt=0 into buf 0
#pragma unroll
  for (int i = 0; i < 4; i++) { gl_lds16(gcur[i], SM + loff[i]); gcur[i] += gstep[i]; }

  for (int kt = 0; kt <= ktmax; kt++) {
    __syncthreads();   // drains this wave's loads; all waves done reading other buf
    if (kt < ktmax) {
#pragma unroll
      for (int i = 0; i < 4; i++) {
        gl_lds16(gcur[i], SM + (cur ^ 1) * 8192 + loff[i]);
        gcur[i] += gstep[i];
      }
    }
    const u16* Kbuf = SM + cur * 8192;
    const u16* Vbuf = Kbuf + 4096;

    // S = Q K^T
    bf16x8 bk[4][2];
#pragma unroll
    for (int ct = 0; ct < 4; ct++)
#pragma unroll
      for (int half = 0; half < 2; half++)
        bk[ct][half] = *(const bf16x8*)(Kbuf + half * 2048 + (ct * 16 + lrow) * 32 + lk * 8);
    floatx4 sf[2][4] = {};
#pragma unroll
    for (int sub = 0; sub < 2; sub++)
#pragma unroll
      for (int ct = 0; ct < 4; ct++) {
        sf[sub][ct] = __builtin_amdgcn_mfma_f32_16x16x32_bf16(aq[sub][0], bk[ct][0],
                                                              sf[sub][ct], 0, 0, 0);
        sf[sub][ct] = __builtin_amdgcn_mfma_f32_16x16x32_bf16(aq[sub][1], bk[ct][1],
                                                              sf[sub][ct], 0, 0, 0);
      }

    // mask + exp -> P (swizzled LDS), den
#pragma unroll
    for (int sub = 0; sub < 2; sub++)
#pragma unroll
      for (int ct = 0; ct < 4; ct++) {
        const int kpos = kt * 64 + ct * 16 + lrow;
#pragma unroll
        for (int r = 0; r < 4; r++) {
          const int qpos = qbase + sub * 16 + lk * 4 + r;
          const float p = (kpos < qpos) ? __expf(sf[sub][ct][r] * 0.125f) : 0.f;
          den[sub][r] += p;
          const int prow = sub * 16 + lk * 4 + r;
          const int pcol = ct * 16 + lrow;
          Pw[prow * 64 + ((((pcol >> 3) ^ (prow & 7))) << 3) + (pcol & 7)] = f2bf(p);
        }
      }

    // O += P V  (P as A-operand from LDS, V^T rows as B-operand)
    bf16x8 ap[2][2], bv[4][2];
#pragma unroll
    for (int sub = 0; sub < 2; sub++)
#pragma unroll
      for (int kh = 0; kh < 2; kh++) {
        const int prow = sub * 16 + lrow;
        ap[sub][kh] = *(const bf16x8*)(Pw + prow * 64 + (((kh * 4 + lk) ^ (prow & 7)) << 3));
      }
#pragma unroll
    for (int ni = 0; ni < 4; ni++)
#pragma unroll
      for (int kh = 0; kh < 2; kh++)
        bv[ni][kh] = *(const bf16x8*)(Vbuf + kh * 2048 + (ni * 16 + lrow) * 32 + lk * 8);
#pragma unroll
    for (int sub = 0; sub < 2; sub++)
#pragma unroll
      for (int ni = 0; ni < 4; ni++) {
        oacc[sub][ni] = __builtin_amdgcn_mfma_f32_16x16x32_bf16(ap[sub][0], bv[ni][0],
                                                                oacc[sub][ni], 0, 0, 0);
        oacc[sub][ni] = __builtin_amdgcn_mfma_f32_16x16x32_bf16(ap[sub][1], bv[ni][1],
                                                                oacc[sub][ni], 0, 0, 0);
      }
    cur ^= 1;
  }

  // reduce den over the 16 lanes sharing a q-row group
#pragma unroll
  for (int sub = 0; sub < 2; sub++)
#pragma unroll
    for (int r = 0; r < 4; r++) {
      float d = den[sub][r];
      d += __shfl_xor(d, 1);
      d += __shfl_xor(d, 2);
      d += __shfl_xor(d, 4);
      d += __shfl_xor(d, 8);
      den[sub][r] = d;
    }
#pragma unroll
  for (int sub = 0; sub < 2; sub++)
#pragma unroll
    for (int ni = 0; ni < 4; ni++)
#pragma unroll
      for (int r = 0; r < 4; r++) {
        const int row = qbase + sub * 16 + lk * 4 + r;
        const int col = h * 64 + ni * 16 + lrow;
        av[(size_t)(b * S_ + row) * 1024 + col] = f2bf(oacc[sub][ni][r] / (den[sub][r] + 1e-9f));
      }
}

// ---------------------------------------------------------------------------
// Workspace layout (bytes)
// ---------------------------------------------------------------------------
#define OFF_WQKV 0u            // [3072][1024] bf16
#define OFF_WO   6291456u      // [1024][1024] bf16
#define OFF_WGU  8388608u      // [8192][1024] bf16 (gate/up 16-col interleaved)
#define OFF_WDN  25165824u     // [1024][4096] bf16
#define OFF_H1   33554432u     // [4096][1024] bf16
#define OFF_QKV  41943040u     // [4096][3072] bf16
#define OFF_VT   67108864u     // [2][16][64][2048] bf16
#define OFF_AV   75497472u     // [4096][1024] bf16
#define OFF_X1   83886080u     // [4096][1024] f32
#define OFF_H2   100663296u    // [4096][1024] bf16
#define OFF_HID  109051904u    // [4096][4096] bf16

extern "C" void kernel_launch(void* const* d_in, const int* in_sizes, int n_in,
                              void* d_out, int out_size, void* d_ws, size_t ws_size,
                              hipStream_t stream) {
  const float* x      = (const float*)d_in[0];
  const float* w_q    = (const float*)d_in[1];
  const float* w_k    = (const float*)d_in[2];
  const float* w_v    = (const float*)d_in[3];
  const float* w_o    = (const float*)d_in[4];
  const float* w_gate = (const float*)d_in[5];
  const float* w_up   = (const float*)d_in[6];
  const float* w_down = (const float*)d_in[7];
  const float* g1     = (const float*)d_in[8];
  const float* g2     = (const float*)d_in[9];

  char* ws = (char*)d_ws;
  u16* wqkv_t = (u16*)(ws + OFF_WQKV);
  u16* wo_t   = (u16*)(ws + OFF_WO);
  u16* wgu_t  = (u16*)(ws + OFF_WGU);
  u16* wdn_t  = (u16*)(ws + OFF_WDN);
  u16* h1     = (u16*)(ws + OFF_H1);
  u16* qkv    = (u16*)(ws + OFF_QKV);
  u16* vT     = (u16*)(ws + OFF_VT);
  u16* av     = (u16*)(ws + OFF_AV);
  float* x1   = (float*)(ws + OFF_X1);
  u16* h2     = (u16*)(ws + OFF_H2);
  u16* hid    = (u16*)(ws + OFF_HID);
  float* out  = (float*)d_out;

  const dim3 tb32(32, 8);
  transpose_cast<<<dim3(32, 32), tb32, 0, stream>>>(w_q, wqkv_t, 1024, 1024, 0);
  transpose_cast<<<dim3(32, 32), tb32, 0, stream>>>(w_k, wqkv_t + 1024 * 1024, 1024, 1024, 0);
  transpose_cast<<<dim3(32, 32), tb32, 0, stream>>>(w_v, wqkv_t + 2 * 1024 * 1024, 1024, 1024, 0);
  transpose_cast<<<dim3(32, 32), tb32, 0, stream>>>(w_o, wo_t, 1024, 1024, 0);
  transpose_cast<<<dim3(128, 32), tb32, 0, stream>>>(w_gate, wgu_t, 1024, 4096, 1);
  transpose_cast<<<dim3(128, 32), tb32, 0, stream>>>(w_up, wgu_t, 1024, 4096, 2);
  transpose_cast<<<dim3(32, 128), tb32, 0, stream>>>(w_down, wdn_t, 4096, 1024, 0);

  rmsnorm_kernel<<<BS_, 256, 0, stream>>>(x, g1, h1);
  gemm_bt<128, 0><<<dim3(3072 / 128, BS_ / 128), 256, 0, stream>>>(h1, wqkv_t, qkv, nullptr,
                                                                   BS_, 3072, 1024);
  vtrans_kernel<<<dim3(S_ / 64, H_, B_), 256, 0, stream>>>(qkv, vT);
  attn_kernel<<<dim3(32, 16), 256, 0, stream>>>(qkv, vT, av);
  gemm_bt<64, 1><<<dim3(1024 / 64, BS_ / 128), 256, 0, stream>>>(av, wo_t, x1, x,
                                                                 BS_, 1024, 1024);
  rmsnorm_kernel<<<BS_, 256, 0, stream>>>(x1, g2, h2);
  gemm_bt<128, 2><<<dim3(8192 / 128, BS_ / 128), 256, 0, stream>>>(h2, wgu_t, hid, nullptr,
                                                                   BS_, 8192, 1024);
  gemm_bt<64, 1><<<dim3(1024 / 64, BS_ / 128), 256, 0, stream>>>(hid, wdn_t, out, x1,
                                                                 BS_, 1024, 4096);
}

// Round 3
// 387.378 us; speedup vs baseline: 1.3866x; 1.1753x over previous
//
#include <hip/hip_runtime.h>
#include <cstdint>
#include <cstddef>

typedef unsigned short u16;
typedef unsigned int u32;
typedef __bf16 bf16x8 __attribute__((ext_vector_type(8)));
typedef float floatx4 __attribute__((ext_vector_type(4)));
typedef float floatx16 __attribute__((ext_vector_type(16)));

#define B_ 2
#define S_ 2048
#define D_ 1024
#define H_ 16
#define DFF_ 4096
#define BS_ 4096   // B_*S_

__device__ __forceinline__ u16 f2bf(float f) {
  u32 u = __builtin_bit_cast(u32, f);
  u += 0x7fffu + ((u >> 16) & 1u);
  return (u16)(u >> 16);
}
__device__ __forceinline__ float bf2f(u16 h) {
  u32 u = ((u32)h) << 16;
  return __builtin_bit_cast(float, u);
}

// async global->LDS, 16B per lane; LDS dest is wave-uniform base + lane*16
__device__ __forceinline__ void gl_lds16(const u16* g, u16* l) {
  __builtin_amdgcn_global_load_lds(
      (const __attribute__((address_space(1))) void*)g,
      (__attribute__((address_space(3))) void*)l, 16, 0, 0);
}

// ---------------------------------------------------------------------------
// All weight transposes (+bf16 cast) in ONE kernel.  32x32 LDS tiles.
// mode 0: out row = col. mode 1/2 (gate/up): 32-col interleave ->
//   row' = (c>>5)*64 + (c&31) (+32 for up), so gemm waves see gate|up pairs.
// ---------------------------------------------------------------------------
__global__ void prep_weights(const float* __restrict__ wq, const float* __restrict__ wk,
                             const float* __restrict__ wv, const float* __restrict__ wo,
                             const float* __restrict__ wg, const float* __restrict__ wu,
                             const float* __restrict__ wd,
                             u16* __restrict__ wqkv_t, u16* __restrict__ wo_t,
                             u16* __restrict__ wgu_t, u16* __restrict__ wdn_t) {
  __shared__ float tile[32][33];
  const int id = blockIdx.x;
  const float* src;
  u16* dst;
  int R, C, bx, by, mode;
  if (id < 3072) {
    const int which = id >> 10, lo = id & 1023;
    src = which == 0 ? wq : (which == 1 ? wk : wv);
    dst = wqkv_t + which * 1024 * 1024;
    R = 1024; C = 1024; bx = lo & 31; by = lo >> 5; mode = 0;
  } else if (id < 4096) {
    const int lo = id - 3072;
    src = wo; dst = wo_t; R = 1024; C = 1024; bx = lo & 31; by = lo >> 5; mode = 0;
  } else if (id < 8192) {
    const int lo = id - 4096;
    src = wg; dst = wgu_t; R = 1024; C = 4096; bx = lo & 127; by = lo >> 7; mode = 1;
  } else if (id < 12288) {
    const int lo = id - 8192;
    src = wu; dst = wgu_t; R = 1024; C = 4096; bx = lo & 127; by = lo >> 7; mode = 2;
  } else {
    const int lo = id - 12288;
    src = wd; dst = wdn_t; R = 4096; C = 1024; bx = lo & 31; by = lo >> 5; mode = 0;
  }
  const int tx = threadIdx.x, ty = threadIdx.y;
  const int c0 = bx * 32, r0 = by * 32;
#pragma unroll
  for (int i = 0; i < 4; i++)
    tile[ty + i * 8][tx] = src[(size_t)(r0 + ty + i * 8) * C + c0 + tx];
  __syncthreads();
#pragma unroll
  for (int i = 0; i < 4; i++) {
    const int oc = c0 + ty + i * 8;
    const int orow = (mode == 0) ? oc
                                 : ((oc >> 5) * 64 + (oc & 31) + (mode == 2 ? 32 : 0));
    dst[(size_t)orow * R + r0 + tx] = f2bf(tile[tx][ty + i * 8]);
  }
}

// ---------------------------------------------------------------------------
// RMSNorm: x [rows][1024] f32, g [1024] f32 -> out bf16 [rows][1024]
// ---------------------------------------------------------------------------
__global__ __launch_bounds__(256) void rmsnorm_kernel(const float* __restrict__ x,
                                                      const float* __restrict__ g,
                                                      u16* __restrict__ out) {
  const int row = blockIdx.x, t = threadIdx.x;
  const float4 v = ((const float4*)(x + (size_t)row * 1024))[t];
  float ss = v.x * v.x + v.y * v.y + v.z * v.z + v.w * v.w;
#pragma unroll
  for (int off = 32; off > 0; off >>= 1) ss += __shfl_xor(ss, off);
  __shared__ float red[4];
  if ((t & 63) == 0) red[t >> 6] = ss;
  __syncthreads();
  ss = red[0] + red[1] + red[2] + red[3];
  const float inv = rsqrtf(ss * (1.0f / 1024.0f) + 1e-6f);
  const float4 gv = ((const float4*)g)[t];
  uint2 o;
  o.x = (u32)f2bf(v.x * inv * gv.x) | ((u32)f2bf(v.y * inv * gv.y) << 16);
  o.y = (u32)f2bf(v.z * inv * gv.z) | ((u32)f2bf(v.w * inv * gv.w) << 16);
  ((uint2*)(out + (size_t)row * 1024))[t] = o;
}

// ---------------------------------------------------------------------------
// V^T: qkv v-block [b,s,h,dv] -> vT [b][h][dv=64][S].  64x64 LDS tile.
// ---------------------------------------------------------------------------
__global__ __launch_bounds__(256) void vtrans_kernel(const u16* __restrict__ qkv,
                                                     u16* __restrict__ vT) {
  __shared__ u16 tile[64][72];
  const int t = threadIdx.x;
  const int s0 = blockIdx.x * 64, h = blockIdx.y, b = blockIdx.z;
  const int r = t >> 2, cc = t & 3;
  const u16* src = qkv + (size_t)(b * S_ + s0 + r) * 3072 + 2 * D_ + h * 64 + cc * 16;
  *(uint4*)(&tile[r][cc * 16]) = *(const uint4*)src;
  *(uint4*)(&tile[r][cc * 16 + 8]) = *(const uint4*)(src + 8);
  __syncthreads();
  union { uint4 u[2]; u16 s[16]; } o;
#pragma unroll
  for (int j = 0; j < 16; j++) o.s[j] = tile[cc * 16 + j][r];
  u16* dst = vT + (size_t)((b * H_ + h) * 64 + r) * S_ + s0 + cc * 16;
  *(uint4*)dst = o.u[0];
  *(uint4*)(dst + 8) = o.u[1];
}

// ---------------------------------------------------------------------------
// bf16 GEMM: C[M,N] = A[M,K] @ Bt[N,K]^T.
// 32x32x16 MFMA, BK=64, 128xBN tile, 4 waves (2x2), wave tile 64x(BN/2).
// global_load_lds staging with XOR chunk swizzle: LDS slot for (row, chunk c)
// is row*64 + ((c ^ (row&7))*8) u16 -> all fragment ds_read_b128 conflict-free.
// Staging lane j of a 8-row segment loads global chunk (j&7)^(j>>3) so the
// lane-linear LDS scatter lands data in swizzled position.
// EPI 0: bf16 out. EPI 1: f32 out + f32 residual. EPI 2: silu(gate)*up (BN=128,
// gate/up interleaved in 32-col blocks) -> bf16 [M][4096].
// ---------------------------------------------------------------------------
template <int BN, int EPI>
__global__ __launch_bounds__(256) void gemm_bt(const u16* __restrict__ A,
                                               const u16* __restrict__ Bt,
                                               void* __restrict__ Cout,
                                               const float* __restrict__ res,
                                               int M, int N, int K) {
  __shared__ u16 As[128 * 64];
  __shared__ u16 Bs[BN * 64];
  constexpr int NTI = BN / 64;        // n-subtiles of 32 per wave
  constexpr int NSEG = 16 + BN / 8;   // 1024B staging segments
  constexpr int SPW = NSEG / 4;
  const int t = threadIdx.x, w = t >> 6, l = t & 63;
  const int m0 = blockIdx.y * 128, n0 = blockIdx.x * BN;
  const int wm = w >> 1, wn = w & 1;
  const int c31 = l & 31, khalf = l >> 5;

  const u16* gsrc[SPW];
  u16* ldst[SPW];
  {
    const int rl = l >> 3, ch = (l & 7) ^ rl;
#pragma unroll
    for (int i = 0; i < SPW; i++) {
      const int s = w * SPW + i;
      if (s < 16) {
        gsrc[i] = A + (size_t)(m0 + s * 8 + rl) * K + ch * 8;
        ldst[i] = As + s * 512;
      } else {
        gsrc[i] = Bt + (size_t)(n0 + (s - 16) * 8 + rl) * K + ch * 8;
        ldst[i] = Bs + (s - 16) * 512;
      }
    }
  }

  floatx16 acc[2][NTI] = {};

  for (int kk = 0; kk < K; kk += 64) {
    __syncthreads();
#pragma unroll
    for (int i = 0; i < SPW; i++) gl_lds16(gsrc[i], ldst[i]);
#pragma unroll
    for (int i = 0; i < SPW; i++) gsrc[i] += 64;
    __syncthreads();

#pragma unroll
    for (int ks = 0; ks < 4; ks++) {
      bf16x8 af[2], bfr[NTI];
#pragma unroll
      for (int mi = 0; mi < 2; mi++) {
        const int row = wm * 64 + mi * 32 + c31;
        const int e = (ks * 2 + khalf) ^ (row & 7);
        af[mi] = *(const bf16x8*)(As + row * 64 + e * 8);
      }
#pragma unroll
      for (int ni = 0; ni < NTI; ni++) {
        const int row = wn * (BN / 2) + ni * 32 + c31;
        const int e = (ks * 2 + khalf) ^ (row & 7);
        bfr[ni] = *(const bf16x8*)(Bs + row * 64 + e * 8);
      }
#pragma unroll
      for (int mi = 0; mi < 2; mi++)
#pragma unroll
        for (int ni = 0; ni < NTI; ni++)
          acc[mi][ni] = __builtin_amdgcn_mfma_f32_32x32x16_bf16(af[mi], bfr[ni],
                                                                acc[mi][ni], 0, 0, 0);
    }
  }

  // C/D layout (32x32): col = lane&31, row = (reg&3) + 8*(reg>>2) + 4*(lane>>5)
  if (EPI == 2) {
#pragma unroll
    for (int mi = 0; mi < 2; mi++) {
      const int colo = ((int)blockIdx.x * 2 + wn) * 32 + c31;
#pragma unroll
      for (int reg = 0; reg < 16; reg++) {
        const int row = m0 + wm * 64 + mi * 32 + (reg & 3) + 8 * (reg >> 2) + 4 * khalf;
        const float g = acc[mi][0][reg];
        const float u = acc[mi][1][reg];
        ((u16*)Cout)[(size_t)row * 4096 + colo] = f2bf(g / (1.f + __expf(-g)) * u);
      }
    }
  } else {
#pragma unroll
    for (int mi = 0; mi < 2; mi++)
#pragma unroll
      for (int ni = 0; ni < NTI; ni++) {
        const int col = n0 + wn * (BN / 2) + ni * 32 + c31;
#pragma unroll
        for (int reg = 0; reg < 16; reg++) {
          const int row = m0 + wm * 64 + mi * 32 + (reg & 3) + 8 * (reg >> 2) + 4 * khalf;
          const size_t idx = (size_t)row * N + col;
          if (EPI == 0) ((u16*)Cout)[idx] = f2bf(acc[mi][ni][reg]);
          else          ((float*)Cout)[idx] = acc[mi][ni][reg] + res[idx];
        }
      }
  }
}

// ---------------------------------------------------------------------------
// Causal attention (strict k<q), softmax = exp(s)/(sum+1e-9), flash-style.
// q-tile 128 (wave owns 32 q rows), k-tile 64, double-buffered LDS staging of
// K [half][64][32] and V^T [khalf][64][32] via global_load_lds; one barrier
// per iter; P per-wave in XOR-swizzled LDS.
// ---------------------------------------------------------------------------
__global__ __launch_bounds__(256) void attn_kernel(const u16* __restrict__ qkv,
                                                   const u16* __restrict__ vT,
                                                   u16* __restrict__ av) {
  __shared__ u16 SM[2 * 8192];       // [buf][ K:2x64x32 | V:2x64x32 ]
  __shared__ u16 Ps[4 * 2048];       // per-wave P [32 q][64 k], 16B-chunk swizzle
  const int t = threadIdx.x, w = t >> 6, l = t & 63;
  const int lrow = l & 15, lk = l >> 4;
  const int bh = blockIdx.x;         // b*16 + h
  const int b = bh >> 4, h = bh & 15;
  const int qt = 15 - (int)blockIdx.y;   // heavy tiles dispatch first
  const int qbase = qt * 128 + w * 32;
  const int ktmax = 2 * qt + 1;
  u16* Pw = Ps + w * 2048;

  bf16x8 aq[2][2];
#pragma unroll
  for (int sub = 0; sub < 2; sub++)
#pragma unroll
    for (int half = 0; half < 2; half++)
      aq[sub][half] = *(const bf16x8*)(qkv + (size_t)(b * S_ + qbase + sub * 16 + lrow) * 3072 +
                                       h * 64 + half * 32 + lk * 8);

  const u16* gcur[4];
  int gstep[4], loff[4];
#pragma unroll
  for (int i = 0; i < 4; i++) {
    const int c = w + 4 * i;
    const int half = (c >> 2) & 1, grp = c & 3;
    if (c < 8) {
      gcur[i] = qkv + (size_t)(b * S_ + grp * 16 + (l >> 2)) * 3072 + D_ + h * 64 +
                half * 32 + (l & 3) * 8;
      gstep[i] = 64 * 3072;
      loff[i] = half * 2048 + grp * 512;
    } else {
      gcur[i] = vT + (size_t)(bh * 64 + grp * 16 + (l >> 2)) * S_ + half * 32 + (l & 3) * 8;
      gstep[i] = 64;
      loff[i] = 4096 + half * 2048 + grp * 512;
    }
  }

  floatx4 oacc[2][4] = {};
  float den[2][4] = {};

  int cur = 0;
#pragma unroll
  for (int i = 0; i < 4; i++) { gl_lds16(gcur[i], SM + loff[i]); gcur[i] += gstep[i]; }

  for (int kt = 0; kt <= ktmax; kt++) {
    __syncthreads();
    if (kt < ktmax) {
#pragma unroll
      for (int i = 0; i < 4; i++) {
        gl_lds16(gcur[i], SM + (cur ^ 1) * 8192 + loff[i]);
        gcur[i] += gstep[i];
      }
    }
    const u16* Kbuf = SM + cur * 8192;
    const u16* Vbuf = Kbuf + 4096;

    bf16x8 bk[4][2];
#pragma unroll
    for (int ct = 0; ct < 4; ct++)
#pragma unroll
      for (int half = 0; half < 2; half++)
        bk[ct][half] = *(const bf16x8*)(Kbuf + half * 2048 + (ct * 16 + lrow) * 32 + lk * 8);
    floatx4 sf[2][4] = {};
#pragma unroll
    for (int sub = 0; sub < 2; sub++)
#pragma unroll
      for (int ct = 0; ct < 4; ct++) {
        sf[sub][ct] = __builtin_amdgcn_mfma_f32_16x16x32_bf16(aq[sub][0], bk[ct][0],
                                                              sf[sub][ct], 0, 0, 0);
        sf[sub][ct] = __builtin_amdgcn_mfma_f32_16x16x32_bf16(aq[sub][1], bk[ct][1],
                                                              sf[sub][ct], 0, 0, 0);
      }

#pragma unroll
    for (int sub = 0; sub < 2; sub++)
#pragma unroll
      for (int ct = 0; ct < 4; ct++) {
        const int kpos = kt * 64 + ct * 16 + lrow;
#pragma unroll
        for (int r = 0; r < 4; r++) {
          const int qpos = qbase + sub * 16 + lk * 4 + r;
          const float p = (kpos < qpos) ? __expf(sf[sub][ct][r] * 0.125f) : 0.f;
          den[sub][r] += p;
          const int prow = sub * 16 + lk * 4 + r;
          const int pcol = ct * 16 + lrow;
          Pw[prow * 64 + ((((pcol >> 3) ^ (prow & 7))) << 3) + (pcol & 7)] = f2bf(p);
        }
      }

    bf16x8 ap[2][2], bv[4][2];
#pragma unroll
    for (int sub = 0; sub < 2; sub++)
#pragma unroll
      for (int kh = 0; kh < 2; kh++) {
        const int prow = sub * 16 + lrow;
        ap[sub][kh] = *(const bf16x8*)(Pw + prow * 64 + (((kh * 4 + lk) ^ (prow & 7)) << 3));
      }
#pragma unroll
    for (int ni = 0; ni < 4; ni++)
#pragma unroll
      for (int kh = 0; kh < 2; kh++)
        bv[ni][kh] = *(const bf16x8*)(Vbuf + kh * 2048 + (ni * 16 + lrow) * 32 + lk * 8);
#pragma unroll
    for (int sub = 0; sub < 2; sub++)
#pragma unroll
      for (int ni = 0; ni < 4; ni++) {
        oacc[sub][ni] = __builtin_amdgcn_mfma_f32_16x16x32_bf16(ap[sub][0], bv[ni][0],
                                                                oacc[sub][ni], 0, 0, 0);
        oacc[sub][ni] = __builtin_amdgcn_mfma_f32_16x16x32_bf16(ap[sub][1], bv[ni][1],
                                                                oacc[sub][ni], 0, 0, 0);
      }
    cur ^= 1;
  }

#pragma unroll
  for (int sub = 0; sub < 2; sub++)
#pragma unroll
    for (int r = 0; r < 4; r++) {
      float d = den[sub][r];
      d += __shfl_xor(d, 1);
      d += __shfl_xor(d, 2);
      d += __shfl_xor(d, 4);
      d += __shfl_xor(d, 8);
      den[sub][r] = d;
    }
#pragma unroll
  for (int sub = 0; sub < 2; sub++)
#pragma unroll
    for (int ni = 0; ni < 4; ni++)
#pragma unroll
      for (int r = 0; r < 4; r++) {
        const int row = qbase + sub * 16 + lk * 4 + r;
        const int col = h * 64 + ni * 16 + lrow;
        av[(size_t)(b * S_ + row) * 1024 + col] = f2bf(oacc[sub][ni][r] / (den[sub][r] + 1e-9f));
      }
}

// ---------------------------------------------------------------------------
// Workspace layout (bytes)
// ---------------------------------------------------------------------------
#define OFF_WQKV 0u            // [3072][1024] bf16
#define OFF_WO   6291456u      // [1024][1024] bf16
#define OFF_WGU  8388608u      // [8192][1024] bf16 (gate/up 32-col interleaved)
#define OFF_WDN  25165824u     // [1024][4096] bf16
#define OFF_H1   33554432u     // [4096][1024] bf16
#define OFF_QKV  41943040u     // [4096][3072] bf16
#define OFF_VT   67108864u     // [2][16][64][2048] bf16
#define OFF_AV   75497472u     // [4096][1024] bf16
#define OFF_X1   83886080u     // [4096][1024] f32
#define OFF_H2   100663296u    // [4096][1024] bf16
#define OFF_HID  109051904u    // [4096][4096] bf16

extern "C" void kernel_launch(void* const* d_in, const int* in_sizes, int n_in,
                              void* d_out, int out_size, void* d_ws, size_t ws_size,
                              hipStream_t stream) {
  const float* x      = (const float*)d_in[0];
  const float* w_q    = (const float*)d_in[1];
  const float* w_k    = (const float*)d_in[2];
  const float* w_v    = (const float*)d_in[3];
  const float* w_o    = (const float*)d_in[4];
  const float* w_gate = (const float*)d_in[5];
  const float* w_up   = (const float*)d_in[6];
  const float* w_down = (const float*)d_in[7];
  const float* g1     = (const float*)d_in[8];
  const float* g2     = (const float*)d_in[9];

  char* ws = (char*)d_ws;
  u16* wqkv_t = (u16*)(ws + OFF_WQKV);
  u16* wo_t   = (u16*)(ws + OFF_WO);
  u16* wgu_t  = (u16*)(ws + OFF_WGU);
  u16* wdn_t  = (u16*)(ws + OFF_WDN);
  u16* h1     = (u16*)(ws + OFF_H1);
  u16* qkv    = (u16*)(ws + OFF_QKV);
  u16* vT     = (u16*)(ws + OFF_VT);
  u16* av     = (u16*)(ws + OFF_AV);
  float* x1   = (float*)(ws + OFF_X1);
  u16* h2     = (u16*)(ws + OFF_H2);
  u16* hid    = (u16*)(ws + OFF_HID);
  float* out  = (float*)d_out;

  prep_weights<<<16384, dim3(32, 8), 0, stream>>>(w_q, w_k, w_v, w_o, w_gate, w_up, w_down,
                                                  wqkv_t, wo_t, wgu_t, wdn_t);

  rmsnorm_kernel<<<BS_, 256, 0, stream>>>(x, g1, h1);
  gemm_bt<128, 0><<<dim3(3072 / 128, BS_ / 128), 256, 0, stream>>>(h1, wqkv_t, qkv, nullptr,
                                                                   BS_, 3072, 1024);
  vtrans_kernel<<<dim3(S_ / 64, H_, B_), 256, 0, stream>>>(qkv, vT);
  attn_kernel<<<dim3(32, 16), 256, 0, stream>>>(qkv, vT, av);
  gemm_bt<64, 1><<<dim3(1024 / 64, BS_ / 128), 256, 0, stream>>>(av, wo_t, x1, x,
                                                                 BS_, 1024, 1024);
  rmsnorm_kernel<<<BS_, 256, 0, stream>>>(x1, g2, h2);
  gemm_bt<128, 2><<<dim3(8192 / 128, BS_ / 128), 256, 0, stream>>>(h2, wgu_t, hid, nullptr,
                                                                   BS_, 8192, 1024);
  gemm_bt<64, 1><<<dim3(1024 / 64, BS_ / 128), 256, 0, stream>>>(hid, wdn_t, out, x1,
                                                                 BS_, 1024, 4096);
}